// Round 5
// baseline (454.897 us; speedup 1.0000x reference)
//
#include <hip/hip_runtime.h>

typedef float f32x4v __attribute__((ext_vector_type(4)));

// ---------------------------------------------------------------------------
// Established (R0-R4 forensics): inputs fp32, OUTPUT fp32 (R1/R3/R4 wrote bf16
// and failed bit-identically at 2.726562 -- the fp32 reinterpretation of our
// identical correct bf16 values; checker's "bf16" label is hardcoded and its
// traceback shows all dtype branches, not the taken one).
//
// Fully fused, workspace-free (R4 structure; only the store dtype changed).
// Math: h[bn,i,j,f] = Up[bn,i,f] + V[bn,j,f] + delta_ij*Dg[bn,i,f]
//   Up = x_i.W1b + mean.W1e + b1   (W1 cols 128:256 / 512:640)
//   V  = x_j.W1c                   (cols 256:384)
//   Dg = x_i.W1a + mean.W1d        (cols 0:128 / 384:512)
// then LayerNorm_f -> relu -> +delta_ij*bias_p -> x W2^T + b2.
// ---------------------------------------------------------------------------
__global__ __launch_bounds__(256) void fused_all(
    const float* __restrict__ x, const float* __restrict__ W1,
    const float* __restrict__ b1, const float* __restrict__ gamma,
    const float* __restrict__ beta, const float* __restrict__ bias_p,
    const float* __restrict__ W2, const float* __restrict__ b2,
    float* __restrict__ out)
{
  __shared__ float Xs[64][132];     // x(bn) rows, padded
  __shared__ float W2T[128][132];   // W2T[f][d] = W2[d][f]
  __shared__ float Hs[64][132];     // V, then h, in place
  __shared__ float meanv[128], Upi[128], Dgi[128];
  __shared__ float gam[128], bet[128], bp[128], b2s[128];

  const int tid  = threadIdx.x;
  const int bn   = blockIdx.x >> 6;
  const int i    = blockIdx.x & 63;
  const int lane = tid & 63;
  const int w    = tid >> 6;

  // ---- stage x (64x128 fp32 = 2048 float4, coalesced) ----
  {
    const float4* xv = reinterpret_cast<const float4*>(x + (size_t)bn * 8192);
#pragma unroll
    for (int it = 0; it < 8; ++it) {
      int p = tid + 256 * it;
      int r = p >> 5, c4 = p & 31;
      *reinterpret_cast<float4*>(&Xs[r][4 * c4]) = xv[p];
    }
  }
  // ---- stage W2 transposed ----
  {
    const float4* w2v = reinterpret_cast<const float4*>(W2);
#pragma unroll
    for (int it = 0; it < 16; ++it) {
      int p = tid + 256 * it;            // [0,4096)
      int d = p >> 5, c4 = p & 31;
      float4 v = w2v[p];
      W2T[4 * c4 + 0][d] = v.x;
      W2T[4 * c4 + 1][d] = v.y;
      W2T[4 * c4 + 2][d] = v.z;
      W2T[4 * c4 + 3][d] = v.w;
    }
  }
  if (tid < 128) {
    gam[tid] = gamma[tid];
    bet[tid] = beta[tid];
    bp[tid]  = bias_p[tid];
    b2s[tid] = b2[tid];
  }
  __syncthreads();

  // ---- mean over the 64 rows (axis=2 of x) ----
  if (tid < 128) {
    float s = 0.f;
    for (int r = 0; r < 64; ++r) s += Xs[r][tid];
    meanv[tid] = s * (1.f / 64.f);
  }
  __syncthreads();

  // ---- Up_i[f], Dg_i[f] for this block's row i (tid<128 = f) ----
  if (tid < 128) {
    const float* wr = W1 + (size_t)tid * 640;
    float da = 0.f, ua = 0.f, db = 0.f, ub = 0.f;
    for (int k = 0; k < 128; ++k) {
      float xk = Xs[i][k];
      float mk = meanv[k];
      da += xk * wr[k];          // W1a  -> Dg
      ua += xk * wr[128 + k];    // W1b  -> Up
      db += mk * wr[384 + k];    // W1d  -> Dg
      ub += mk * wr[512 + k];    // W1e  -> Up
    }
    Upi[tid] = ua + ub + b1[tid];
    Dgi[tid] = da + db;
  }

  // ---- V build into Hs: V[j][f] = x_j . W1c_f ----
  {
    const int dq = tid & 31, jo = tid >> 5;
    const int f0 = 4 * dq, j0 = 8 * jo;
    const float4* wr0 = reinterpret_cast<const float4*>(W1 + (size_t)(f0 + 0) * 640 + 256);
    const float4* wr1 = reinterpret_cast<const float4*>(W1 + (size_t)(f0 + 1) * 640 + 256);
    const float4* wr2 = reinterpret_cast<const float4*>(W1 + (size_t)(f0 + 2) * 640 + 256);
    const float4* wr3 = reinterpret_cast<const float4*>(W1 + (size_t)(f0 + 3) * 640 + 256);
    f32x4v acc[8] = {};
    for (int kc = 0; kc < 32; ++kc) {
      float4 w0 = wr0[kc], w1 = wr1[kc], w2 = wr2[kc], w3 = wr3[kc];
#pragma unroll
      for (int jj = 0; jj < 8; ++jj) {
        float4 xr = *reinterpret_cast<const float4*>(&Xs[j0 + jj][4 * kc]);
        acc[jj][0] += xr.x * w0.x + xr.y * w0.y + xr.z * w0.z + xr.w * w0.w;
        acc[jj][1] += xr.x * w1.x + xr.y * w1.y + xr.z * w1.z + xr.w * w1.w;
        acc[jj][2] += xr.x * w2.x + xr.y * w2.y + xr.z * w2.z + xr.w * w2.w;
        acc[jj][3] += xr.x * w3.x + xr.y * w3.y + xr.z * w3.z + xr.w * w3.w;
      }
    }
#pragma unroll
    for (int jj = 0; jj < 8; ++jj)
#pragma unroll
      for (int ff = 0; ff < 4; ++ff)
        Hs[j0 + jj][f0 + ff] = acc[jj][ff];
  }
  __syncthreads();

  // ---- h-build + LN, in place in Hs; wave w owns rows [16w,16w+16) ----
  {
    const int f0 = lane, f1 = lane + 64;
    for (int rr = 0; rr < 16; ++rr) {
      int j = 16 * w + rr;
      float h0 = Upi[f0] + Hs[j][f0];
      float h1 = Upi[f1] + Hs[j][f1];
      if (j == i) { h0 += Dgi[f0]; h1 += Dgi[f1]; }
      float s = h0 + h1;
      float q = h0 * h0 + h1 * h1;
#pragma unroll
      for (int off = 32; off > 0; off >>= 1) {
        s += __shfl_xor(s, off);
        q += __shfl_xor(q, off);
      }
      float mu   = s * (1.f / 128.f);
      float var  = q * (1.f / 128.f) - mu * mu;
      float rstd = rsqrtf(var + 1e-5f);
      h0 = fmaxf((h0 - mu) * rstd * gam[f0] + bet[f0], 0.f);
      h1 = fmaxf((h1 - mu) * rstd * gam[f1] + bet[f1], 0.f);
      if (j == i) { h0 += bp[f0]; h1 += bp[f1]; }
      Hs[j][f0] = h0;
      Hs[j][f1] = h1;
    }
  }
  __syncthreads();

  // ---- final GEMM: out[j][d] = sum_f Hs[j][f] * W2T[f][d] + b2[d] ----
  // fp32 store, full coverage: 64 rows x 128 d = 8192 floats per block.
  {
    const int dq = tid & 31, jo = tid >> 5;
    const int d0 = 4 * dq, j0 = 8 * jo;
    f32x4v acc[8] = {};
    for (int f4 = 0; f4 < 32; ++f4) {
      f32x4v wv[4];
#pragma unroll
      for (int ff = 0; ff < 4; ++ff)
        wv[ff] = *reinterpret_cast<const f32x4v*>(&W2T[4 * f4 + ff][d0]);
#pragma unroll
      for (int jj = 0; jj < 8; ++jj) {
        f32x4v hv = *reinterpret_cast<const f32x4v*>(&Hs[j0 + jj][4 * f4]);
#pragma unroll
        for (int ff = 0; ff < 4; ++ff)
          acc[jj] += hv[ff] * wv[ff];
      }
    }
    const size_t obase = (size_t)blockIdx.x * 8192;
#pragma unroll
    for (int jj = 0; jj < 8; ++jj) {
      float4 ov;
      ov.x = acc[jj][0] + b2s[d0 + 0];
      ov.y = acc[jj][1] + b2s[d0 + 1];
      ov.z = acc[jj][2] + b2s[d0 + 2];
      ov.w = acc[jj][3] + b2s[d0 + 3];
      *reinterpret_cast<float4*>(out + obase + (size_t)(j0 + jj) * 128 + d0) = ov;
    }
  }
}

extern "C" void kernel_launch(void* const* d_in, const int* in_sizes, int n_in,
                              void* d_out, int out_size, void* d_ws, size_t ws_size,
                              hipStream_t stream) {
  const float* x      = (const float*)d_in[0];
  const float* W1     = (const float*)d_in[1];
  const float* b1     = (const float*)d_in[2];
  const float* gamma  = (const float*)d_in[3];
  const float* beta   = (const float*)d_in[4];
  const float* bias_p = (const float*)d_in[5];
  const float* W2     = (const float*)d_in[6];
  const float* b2     = (const float*)d_in[7];

  fused_all<<<2048, 256, 0, stream>>>(x, W1, b1, gamma, beta, bias_p, W2, b2,
                                      (float*)d_out);
}

// Round 6
// 120.970 us; speedup vs baseline: 3.7604x; 3.7604x over previous
//
#include <hip/hip_runtime.h>

typedef __bf16 bf16x4 __attribute__((ext_vector_type(4)));
typedef __bf16 bf16x8 __attribute__((ext_vector_type(8)));
typedef float  f32x4v __attribute__((ext_vector_type(4)));

#define HS 136   // padded row stride (bf16 halfwords): 272 B, 16B-aligned, conflict-min

// ---------------------------------------------------------------------------
// Established: inputs fp32, output fp32 (R5 passed). R5 was occupancy-bound
// VALU with 64x-redundant V recompute. Split:
//  K1 (fp32 VALU, 201 MFLOP): per bn compute Up/V/Dg into ws once; convert
//     W2 -> bf16 ws.
//  K2: LN + diag + bf16 MFMA final GEMM + direct fp32 store.
// h[bn,i,j,f] = Up[bn,i,f] + V[bn,j,f] + delta_ij*Dg[bn,i,f]
//   Up = x_i.W1b + mean.W1e + b1 ; V = x_j.W1c ; Dg = x_i.W1a + mean.W1d
// out = relu(LN_f(h))(+delta_ij*bias_p) @ W2^T + b2
// ---------------------------------------------------------------------------

// K1: grid 256 = 32 bn x 8 row-groups. fp32 exact (LN inputs stay fp32).
__global__ __launch_bounds__(256) void k1_prep(
    const float* __restrict__ x, const float* __restrict__ W1,
    const float* __restrict__ b1, const float* __restrict__ W2,
    float* __restrict__ Up, float* __restrict__ V, float* __restrict__ Dg,
    __bf16* __restrict__ W2b)
{
  __shared__ float Xs[64][132];
  __shared__ float meanv[128], mwd[128], mwe[128];

  const int tid = threadIdx.x;
  const int bn  = blockIdx.x >> 3;
  const int g   = blockIdx.x & 7;

  const float4* xv = reinterpret_cast<const float4*>(x + (size_t)bn * 8192);
#pragma unroll
  for (int it = 0; it < 8; ++it) {
    int p = tid + 256 * it;
    int r = p >> 5, c4 = p & 31;
    *reinterpret_cast<float4*>(&Xs[r][4 * c4]) = xv[p];
  }

  // W2 fp32 -> bf16 ws (32 g==0 blocks write identical bytes: benign)
  if (g == 0) {
    const float4* w2v = reinterpret_cast<const float4*>(W2);
#pragma unroll
    for (int it = 0; it < 16; ++it) {
      int p = tid + 256 * it;            // [0,4096)
      float4 v = w2v[p];
      bf16x4 hv;
      hv[0] = (__bf16)v.x; hv[1] = (__bf16)v.y;
      hv[2] = (__bf16)v.z; hv[3] = (__bf16)v.w;
      reinterpret_cast<bf16x4*>(W2b)[p] = hv;
    }
  }
  __syncthreads();

  if (tid < 128) {
    float s = 0.f;
    for (int r = 0; r < 64; ++r) s += Xs[r][tid];
    meanv[tid] = s * (1.f / 64.f);
  }
  __syncthreads();

  if (tid < 128) {
    const float* wd = W1 + (size_t)tid * 640 + 384;
    const float* we = W1 + (size_t)tid * 640 + 512;
    float ad = 0.f, ae = 0.f;
    for (int k = 0; k < 128; ++k) {
      float mk = meanv[k];
      ad += mk * wd[k];
      ae += mk * we[k];
    }
    mwd[tid] = ad;
    mwe[tid] = ae + b1[tid];
  }
  __syncthreads();

  for (int dd = tid; dd < 384; dd += 256) {
    int part = dd >> 7;                  // 0=W1a->Dg, 1=W1b->Up, 2=W1c->V
    int f    = dd & 127;
    const float4* wrow =
        reinterpret_cast<const float4*>(W1 + (size_t)f * 640 + part * 128);
    float acc[8] = {};
    for (int kc = 0; kc < 32; ++kc) {
      float4 wv = wrow[kc];
#pragma unroll
      for (int r = 0; r < 8; ++r) {
        float4 xr = *reinterpret_cast<const float4*>(&Xs[8 * g + r][4 * kc]);
        acc[r] += xr.x * wv.x + xr.y * wv.y + xr.z * wv.z + xr.w * wv.w;
      }
    }
    float  add = (part == 0) ? mwd[f] : (part == 1 ? mwe[f] : 0.f);
    float* op  = (part == 0) ? Dg : (part == 1 ? Up : V);
#pragma unroll
    for (int r = 0; r < 8; ++r)
      op[((size_t)bn * 64 + 8 * g + r) * 128 + f] = acc[r] + add;
  }
}

// K2: grid 2048 = (bn, i). LDS 52.2 KB -> 3 blocks/CU.
__global__ __launch_bounds__(256) void k2_main(
    const float* __restrict__ Up, const float* __restrict__ V,
    const float* __restrict__ Dg, const __bf16* __restrict__ W2b,
    const float* __restrict__ gamma, const float* __restrict__ beta,
    const float* __restrict__ bias_p, const float* __restrict__ b2,
    float* __restrict__ out)
{
  __shared__ __align__(16) __bf16 W2s[128 * HS];  // 34816 B
  __shared__ __align__(16) __bf16 Hs[64 * HS];    // 17408 B

  const int tid  = threadIdx.x;
  const int bid  = blockIdx.x;
  const int bn   = bid >> 6;
  const int i    = bid & 63;
  const int lane = tid & 63;
  const int w    = tid >> 6;

  // stage W2 bf16 (2048 uint4) into padded LDS
  {
    const uint4* w2v = reinterpret_cast<const uint4*>(W2b);
#pragma unroll
    for (int it = 0; it < 8; ++it) {
      int p   = tid + 256 * it;
      int row = p >> 4;
      int col = (p & 15) * 8;
      *reinterpret_cast<uint4*>(&W2s[row * HS + col]) = w2v[p];
    }
  }

  // h-build + LN: one half-wave per row per iteration (width-32 shuffles)
  {
    const int c    = lane & 31;          // float4 column
    const int half = lane >> 5;
    const size_t base = (size_t)bn * 64;
    const float4 up4 = reinterpret_cast<const float4*>(Up + (base + i) * 128)[c];
    const float4 dg4 = reinterpret_cast<const float4*>(Dg + (base + i) * 128)[c];
    const float4 g4  = reinterpret_cast<const float4*>(gamma)[c];
    const float4 be4 = reinterpret_cast<const float4*>(beta)[c];
    const float4 bp4 = reinterpret_cast<const float4*>(bias_p)[c];
#pragma unroll
    for (int it = 0; it < 8; ++it) {
      int r = 8 * it + 2 * w + half;
      float4 v4 = reinterpret_cast<const float4*>(V + (base + r) * 128)[c];
      float h0 = v4.x + up4.x, h1 = v4.y + up4.y;
      float h2 = v4.z + up4.z, h3 = v4.w + up4.w;
      if (r == i) { h0 += dg4.x; h1 += dg4.y; h2 += dg4.z; h3 += dg4.w; }
      float s = h0 + h1 + h2 + h3;
      float q = h0 * h0 + h1 * h1 + h2 * h2 + h3 * h3;
#pragma unroll
      for (int off = 16; off > 0; off >>= 1) {
        s += __shfl_xor(s, off, 32);
        q += __shfl_xor(q, off, 32);
      }
      float mu   = s * (1.f / 128.f);
      float var  = q * (1.f / 128.f) - mu * mu;
      float rstd = rsqrtf(var + 1e-5f);
      h0 = fmaxf(fmaf((h0 - mu) * rstd, g4.x, be4.x), 0.f);
      h1 = fmaxf(fmaf((h1 - mu) * rstd, g4.y, be4.y), 0.f);
      h2 = fmaxf(fmaf((h2 - mu) * rstd, g4.z, be4.z), 0.f);
      h3 = fmaxf(fmaf((h3 - mu) * rstd, g4.w, be4.w), 0.f);
      if (r == i) { h0 += bp4.x; h1 += bp4.y; h2 += bp4.z; h3 += bp4.w; }
      bf16x4 hv;
      hv[0] = (__bf16)h0; hv[1] = (__bf16)h1;
      hv[2] = (__bf16)h2; hv[3] = (__bf16)h3;
      *reinterpret_cast<bf16x4*>(&Hs[r * HS + 4 * c]) = hv;
    }
  }
  __syncthreads();

  // MFMA: out(64x128) = Hs(64x128bf16) x W2^T ; wave w owns rows 16w..16w+15
  // A[m=lane&15][k=quad*8+j], B[n=lane&15][k=quad*8+j], D[row=quad*4+rg][col=lane&15]
  const int m    = lane & 15;
  const int quad = lane >> 4;
  bf16x8 af[4];
#pragma unroll
  for (int ks = 0; ks < 4; ++ks)
    af[ks] = *reinterpret_cast<const bf16x8*>(
        &Hs[(16 * w + m) * HS + 32 * ks + 8 * quad]);

  const size_t obase = (size_t)bid * 8192;
#pragma unroll
  for (int t = 0; t < 8; ++t) {
    f32x4v a = {0.f, 0.f, 0.f, 0.f};
#pragma unroll
    for (int ks = 0; ks < 4; ++ks) {
      bf16x8 bf = *reinterpret_cast<const bf16x8*>(
          &W2s[(16 * t + m) * HS + 32 * ks + 8 * quad]);
      a = __builtin_amdgcn_mfma_f32_16x16x32_bf16(af[ks], bf, a, 0, 0, 0);
    }
    const int d = 16 * t + m;
    const float b2v = b2[d];
#pragma unroll
    for (int rg = 0; rg < 4; ++rg) {
      int j = 16 * w + 4 * quad + rg;
      out[obase + (size_t)j * 128 + d] = a[rg] + b2v;
    }
  }
}

extern "C" void kernel_launch(void* const* d_in, const int* in_sizes, int n_in,
                              void* d_out, int out_size, void* d_ws, size_t ws_size,
                              hipStream_t stream) {
  const float* x      = (const float*)d_in[0];
  const float* W1     = (const float*)d_in[1];
  const float* b1     = (const float*)d_in[2];
  const float* gamma  = (const float*)d_in[3];
  const float* beta   = (const float*)d_in[4];
  const float* bias_p = (const float*)d_in[5];
  const float* W2     = (const float*)d_in[6];
  const float* b2     = (const float*)d_in[7];

  // ws: Up | V | Dg (each 2048*128 fp32) | W2b (128*128 bf16) = 3 MB + 32 KB
  float*  Up  = (float*)d_ws;
  float*  V   = Up + 2048 * 128;
  float*  Dg  = V + 2048 * 128;
  __bf16* W2b = (__bf16*)(Dg + 2048 * 128);

  k1_prep<<<256, 256, 0, stream>>>(x, W1, b1, W2, Up, V, Dg, W2b);
  k2_main<<<2048, 256, 0, stream>>>(Up, V, Dg, W2b, gamma, beta, bias_p, b2,
                                    (float*)d_out);
}

// Round 7
// 111.606 us; speedup vs baseline: 4.0759x; 1.0839x over previous
//
#include <hip/hip_runtime.h>

typedef __bf16 bf16x4 __attribute__((ext_vector_type(4)));
typedef __bf16 bf16x8 __attribute__((ext_vector_type(8)));
typedef float  f32x4v __attribute__((ext_vector_type(4)));

#define HS 136   // padded row stride in bf16 halfwords (272 B, 16B-aligned)

// ---------------------------------------------------------------------------
// inputs fp32, output fp32. h[bn,i,j,f] = Up[bn,i,f]+V[bn,j,f]+delta_ij*Dg[bn,i,f]
//   Up = x_i.W1b + mean.W1e + b1 ; V = x_j.W1c ; Dg = x_i.W1a + mean.W1d
// out = relu(LN_f(h))(+delta_ij*bias_p) @ W2^T + b2
// K1: split-bf16 MFMA (hi/lo, ~fp32-exact) -> Up/V/Dg fp32 ws + W2->bf16.
// K2: LN + diag + bf16 MFMA GEMM + direct fp32 store (R6-proven layouts).
// ---------------------------------------------------------------------------

// K1: grid 192 = 32 bn x 6 chunks; chunk ch -> part pidx=ch>>1 (0=Dg,1=Up,2=V),
// f-tiles (4ch..4ch+3)&7 of that part.
__global__ __launch_bounds__(256) void k1_prep(
    const float* __restrict__ x, const float* __restrict__ W1,
    const float* __restrict__ b1, const float* __restrict__ W2,
    float* __restrict__ Up, float* __restrict__ V, float* __restrict__ Dg,
    __bf16* __restrict__ W2b)
{
  __shared__ __align__(16) __bf16 Xhi[64 * HS];
  __shared__ __align__(16) __bf16 Xlo[64 * HS];
  __shared__ float msum[128], pm[256], mw[128];

  const int tid  = threadIdx.x;
  const int bn   = blockIdx.x / 6;
  const int ch   = blockIdx.x % 6;
  const int lane = tid & 63;
  const int w    = tid >> 6;
  const int pidx = ch >> 1;

  if (tid < 128) msum[tid] = 0.f;
  __syncthreads();

  // stage x -> hi/lo bf16 LDS + fp32 column sums (atomic)
  {
    const float4* xv = reinterpret_cast<const float4*>(x + (size_t)bn * 8192);
    const int c = tid & 31;
    float4 ps = {0.f, 0.f, 0.f, 0.f};
#pragma unroll
    for (int it = 0; it < 8; ++it) {
      int p = tid + 256 * it;
      int r = p >> 5;
      float4 v = xv[p];
      ps.x += v.x; ps.y += v.y; ps.z += v.z; ps.w += v.w;
      bf16x4 hv, lv;
      hv[0] = (__bf16)v.x; lv[0] = (__bf16)(v.x - (float)hv[0]);
      hv[1] = (__bf16)v.y; lv[1] = (__bf16)(v.y - (float)hv[1]);
      hv[2] = (__bf16)v.z; lv[2] = (__bf16)(v.z - (float)hv[2]);
      hv[3] = (__bf16)v.w; lv[3] = (__bf16)(v.w - (float)hv[3]);
      *reinterpret_cast<bf16x4*>(&Xhi[r * HS + 4 * c]) = hv;
      *reinterpret_cast<bf16x4*>(&Xlo[r * HS + 4 * c]) = lv;
    }
    atomicAdd(&msum[4 * c + 0], ps.x);
    atomicAdd(&msum[4 * c + 1], ps.y);
    atomicAdd(&msum[4 * c + 2], ps.z);
    atomicAdd(&msum[4 * c + 3], ps.w);
  }

  // W2 fp32 -> bf16 ws (ch==4 blocks, identical writes: benign)
  if (ch == 4) {
    const float4* w2v = reinterpret_cast<const float4*>(W2);
#pragma unroll
    for (int it = 0; it < 16; ++it) {
      int p = tid + 256 * it;
      float4 v = w2v[p];
      bf16x4 hv;
      hv[0] = (__bf16)v.x; hv[1] = (__bf16)v.y;
      hv[2] = (__bf16)v.z; hv[3] = (__bf16)v.w;
      reinterpret_cast<bf16x4*>(W2b)[p] = hv;
    }
  }
  __syncthreads();

  // mean matvec (fp32): 2 threads per f, 64 MACs each; msum holds SUMS (x64)
  {
    const int f  = tid & 127;
    const int hh = tid >> 7;
    float acc = 0.f;
    if (pidx < 2) {
      const float4* wv4 = reinterpret_cast<const float4*>(
          W1 + (size_t)f * 640 + (pidx == 0 ? 384 : 512) + hh * 64);
#pragma unroll
      for (int kc = 0; kc < 16; ++kc) {
        float4 wv = wv4[kc];
        int k = hh * 64 + 4 * kc;
        acc += msum[k] * wv.x + msum[k + 1] * wv.y +
               msum[k + 2] * wv.z + msum[k + 3] * wv.w;
      }
    }
    pm[tid] = acc;
  }
  __syncthreads();
  if (tid < 128)
    mw[tid] = (pm[tid] + pm[tid + 128]) * (1.f / 64.f) +
              (pidx == 1 ? b1[tid] : 0.f);
  __syncthreads();

  // MFMA: wave w owns m-rows 16w..16w+15; 4 f-tiles x 4 ks x 3 (hi/lo) MFMAs
  const int m    = lane & 15;
  const int quad = lane >> 4;
  bf16x8 ahi[4], alo[4];
#pragma unroll
  for (int ks = 0; ks < 4; ++ks) {
    ahi[ks] = *reinterpret_cast<const bf16x8*>(&Xhi[(16 * w + m) * HS + 32 * ks + 8 * quad]);
    alo[ks] = *reinterpret_cast<const bf16x8*>(&Xlo[(16 * w + m) * HS + 32 * ks + 8 * quad]);
  }

  float* rout = (pidx == 0) ? Dg : (pidx == 1 ? Up : V);
#pragma unroll
  for (int tt = 0; tt < 4; ++tt) {
    const int fout = (((4 * ch + tt) & 7) * 16) + m;
    const float* wrow = W1 + (size_t)fout * 640 + pidx * 128;
    f32x4v a = {0.f, 0.f, 0.f, 0.f};
#pragma unroll
    for (int ks = 0; ks < 4; ++ks) {
      float4 w0 = *reinterpret_cast<const float4*>(wrow + 32 * ks + 8 * quad);
      float4 w1 = *reinterpret_cast<const float4*>(wrow + 32 * ks + 8 * quad + 4);
      bf16x8 bhi, blo;
      bhi[0] = (__bf16)w0.x; blo[0] = (__bf16)(w0.x - (float)bhi[0]);
      bhi[1] = (__bf16)w0.y; blo[1] = (__bf16)(w0.y - (float)bhi[1]);
      bhi[2] = (__bf16)w0.z; blo[2] = (__bf16)(w0.z - (float)bhi[2]);
      bhi[3] = (__bf16)w0.w; blo[3] = (__bf16)(w0.w - (float)bhi[3]);
      bhi[4] = (__bf16)w1.x; blo[4] = (__bf16)(w1.x - (float)bhi[4]);
      bhi[5] = (__bf16)w1.y; blo[5] = (__bf16)(w1.y - (float)bhi[5]);
      bhi[6] = (__bf16)w1.z; blo[6] = (__bf16)(w1.z - (float)bhi[6]);
      bhi[7] = (__bf16)w1.w; blo[7] = (__bf16)(w1.w - (float)bhi[7]);
      a = __builtin_amdgcn_mfma_f32_16x16x32_bf16(ahi[ks], bhi, a, 0, 0, 0);
      a = __builtin_amdgcn_mfma_f32_16x16x32_bf16(alo[ks], bhi, a, 0, 0, 0);
      a = __builtin_amdgcn_mfma_f32_16x16x32_bf16(ahi[ks], blo, a, 0, 0, 0);
    }
    const float addv = mw[fout];
#pragma unroll
    for (int rg = 0; rg < 4; ++rg) {
      int ii = 16 * w + 4 * quad + rg;
      rout[((size_t)bn * 64 + ii) * 128 + fout] = a[rg] + addv;
    }
  }
}

// K2: grid 2048 = (bn, i). LDS 52.2 KB -> 3 blocks/CU.
__global__ __launch_bounds__(256) void k2_main(
    const float* __restrict__ Up, const float* __restrict__ V,
    const float* __restrict__ Dg, const __bf16* __restrict__ W2b,
    const float* __restrict__ gamma, const float* __restrict__ beta,
    const float* __restrict__ bias_p, const float* __restrict__ b2,
    float* __restrict__ out)
{
  __shared__ __align__(16) __bf16 W2s[128 * HS];
  __shared__ __align__(16) __bf16 Hs[64 * HS];

  const int tid  = threadIdx.x;
  const int bid  = blockIdx.x;
  const int bn   = bid >> 6;
  const int i    = bid & 63;
  const int lane = tid & 63;
  const int w    = tid >> 6;

  // stage W2 bf16 into padded LDS
  {
    const uint4* w2v = reinterpret_cast<const uint4*>(W2b);
#pragma unroll
    for (int it = 0; it < 8; ++it) {
      int p   = tid + 256 * it;
      int row = p >> 4;
      int col = (p & 15) * 8;
      *reinterpret_cast<uint4*>(&W2s[row * HS + col]) = w2v[p];
    }
  }

  // h-build + LN; batch the 8 V-row loads first (independent -> MLP)
  {
    const int c    = lane & 31;
    const int half = lane >> 5;
    const size_t base = (size_t)bn * 64;
    const float4 up4 = reinterpret_cast<const float4*>(Up + (base + i) * 128)[c];
    const float4 dg4 = reinterpret_cast<const float4*>(Dg + (base + i) * 128)[c];
    const float4 g4  = reinterpret_cast<const float4*>(gamma)[c];
    const float4 be4 = reinterpret_cast<const float4*>(beta)[c];
    const float4 bp4 = reinterpret_cast<const float4*>(bias_p)[c];
    float4 v4s[8];
#pragma unroll
    for (int it = 0; it < 8; ++it) {
      int r = 8 * it + 2 * w + half;
      v4s[it] = reinterpret_cast<const float4*>(V + (base + r) * 128)[c];
    }
#pragma unroll
    for (int it = 0; it < 8; ++it) {
      int r = 8 * it + 2 * w + half;
      float4 v4 = v4s[it];
      float h0 = v4.x + up4.x, h1 = v4.y + up4.y;
      float h2 = v4.z + up4.z, h3 = v4.w + up4.w;
      if (r == i) { h0 += dg4.x; h1 += dg4.y; h2 += dg4.z; h3 += dg4.w; }
      float s = h0 + h1 + h2 + h3;
      float q = h0 * h0 + h1 * h1 + h2 * h2 + h3 * h3;
#pragma unroll
      for (int off = 16; off > 0; off >>= 1) {
        s += __shfl_xor(s, off, 32);
        q += __shfl_xor(q, off, 32);
      }
      float mu   = s * (1.f / 128.f);
      float var  = q * (1.f / 128.f) - mu * mu;
      float rstd = rsqrtf(var + 1e-5f);
      h0 = fmaxf(fmaf((h0 - mu) * rstd, g4.x, be4.x), 0.f);
      h1 = fmaxf(fmaf((h1 - mu) * rstd, g4.y, be4.y), 0.f);
      h2 = fmaxf(fmaf((h2 - mu) * rstd, g4.z, be4.z), 0.f);
      h3 = fmaxf(fmaf((h3 - mu) * rstd, g4.w, be4.w), 0.f);
      if (r == i) { h0 += bp4.x; h1 += bp4.y; h2 += bp4.z; h3 += bp4.w; }
      bf16x4 hv;
      hv[0] = (__bf16)h0; hv[1] = (__bf16)h1;
      hv[2] = (__bf16)h2; hv[3] = (__bf16)h3;
      *reinterpret_cast<bf16x4*>(&Hs[r * HS + 4 * c]) = hv;
    }
  }
  __syncthreads();

  // MFMA: out(64x128) = Hs x W2^T; A[m][k=32ks+8quad+j], B[n=m][k], D[4quad+rg][n]
  const int m    = lane & 15;
  const int quad = lane >> 4;
  bf16x8 af[4];
#pragma unroll
  for (int ks = 0; ks < 4; ++ks)
    af[ks] = *reinterpret_cast<const bf16x8*>(
        &Hs[(16 * w + m) * HS + 32 * ks + 8 * quad]);

  const size_t obase = (size_t)bid * 8192;
#pragma unroll
  for (int t = 0; t < 8; ++t) {
    f32x4v a = {0.f, 0.f, 0.f, 0.f};
#pragma unroll
    for (int ks = 0; ks < 4; ++ks) {
      bf16x8 bf = *reinterpret_cast<const bf16x8*>(
          &W2s[(16 * t + m) * HS + 32 * ks + 8 * quad]);
      a = __builtin_amdgcn_mfma_f32_16x16x32_bf16(af[ks], bf, a, 0, 0, 0);
    }
    const int d = 16 * t + m;
    const float b2v = b2[d];
#pragma unroll
    for (int rg = 0; rg < 4; ++rg) {
      int j = 16 * w + 4 * quad + rg;
      out[obase + (size_t)j * 128 + d] = a[rg] + b2v;
    }
  }
}

extern "C" void kernel_launch(void* const* d_in, const int* in_sizes, int n_in,
                              void* d_out, int out_size, void* d_ws, size_t ws_size,
                              hipStream_t stream) {
  const float* x      = (const float*)d_in[0];
  const float* W1     = (const float*)d_in[1];
  const float* b1     = (const float*)d_in[2];
  const float* gamma  = (const float*)d_in[3];
  const float* beta   = (const float*)d_in[4];
  const float* bias_p = (const float*)d_in[5];
  const float* W2     = (const float*)d_in[6];
  const float* b2     = (const float*)d_in[7];

  float*  Up  = (float*)d_ws;
  float*  V   = Up + 2048 * 128;
  float*  Dg  = V + 2048 * 128;
  __bf16* W2b = (__bf16*)(Dg + 2048 * 128);

  k1_prep<<<192, 256, 0, stream>>>(x, W1, b1, W2, Up, V, Dg, W2b);
  k2_main<<<2048, 256, 0, stream>>>(Up, V, Dg, W2b, gamma, beta, bias_p, b2,
                                    (float*)d_out);
}